// Round 3
// baseline (869.081 us; speedup 1.0000x reference)
//
#include <hip/hip_runtime.h>
#include <math.h>

#define N_NODES 100000
#define N_EDGES 1600000
#define NFEAT   128
#define NHID    64
#define NCLASS  16

// ---------------------------------------------------------------------------
// Pipeline:  degree-count -> scan (CSR ptr + deg^{-1/2}) -> CSR fill ->
//            [L1] gemm1 (x@W1) -> gather1 (CSR gather + bias + relu) ->
//            [L2] gemm2 (act1@W2) -> gather2 (CSR gather + bias + log_softmax)
// No float atomics anywhere: aggregation is gather-based over a counting-sort
// CSR built once and reused by both layers.
//
// Workspace layout (256B-aligned offsets), ~66 MiB total:
//   cnt int[N] | ptr int[N] | cursor int[N] | eidx int[E] | dis f32[N]
//   xw f32[N*64] | act1 f32[N*64] | xw2 f32[N*16]
// ---------------------------------------------------------------------------

__global__ void k_zero_cnt(int* __restrict__ cnt) {
    for (int i = blockIdx.x * blockDim.x + threadIdx.x; i < N_NODES;
         i += gridDim.x * blockDim.x)
        cnt[i] = 0;
}

__global__ void k_count(const int* __restrict__ colv, int* __restrict__ cnt) {
    for (int e = blockIdx.x * blockDim.x + threadIdx.x; e < N_EDGES;
         e += gridDim.x * blockDim.x)
        atomicAdd(&cnt[colv[e]], 1);
}

// Single-block scan over N_NODES counts -> ptr/cursor, plus dis = rsqrt(cnt+1).
__global__ __launch_bounds__(1024) void k_scan(const int* __restrict__ cnt,
                                               int* __restrict__ ptr,
                                               int* __restrict__ cursor,
                                               float* __restrict__ dis) {
    __shared__ int sh[1024];
    const int t = threadIdx.x;
    const int chunk = (N_NODES + 1023) / 1024;              // 98
    const int lo = t * chunk;
    const int hi = (lo + chunk < N_NODES) ? lo + chunk : N_NODES;
    int s = 0;
    for (int i = lo; i < hi; ++i) s += cnt[i];
    sh[t] = s;
    __syncthreads();
    for (int off = 1; off < 1024; off <<= 1) {
        int v = 0;
        if (t >= off) v = sh[t - off];
        __syncthreads();
        sh[t] += v;
        __syncthreads();
    }
    int base = sh[t] - s;                                   // exclusive prefix
    for (int i = lo; i < hi; ++i) {
        ptr[i] = base;
        cursor[i] = base;
        dis[i] = rsqrtf((float)(cnt[i] + 1));               // +1 = self-loop
        base += cnt[i];
    }
}

__global__ void k_fill(const int* __restrict__ rowv, const int* __restrict__ colv,
                       int* __restrict__ cursor, int* __restrict__ eidx) {
    for (int e = blockIdx.x * blockDim.x + threadIdx.x; e < N_EDGES;
         e += gridDim.x * blockDim.x) {
        int c = colv[e];
        int p = atomicAdd(&cursor[c], 1);
        eidx[p] = rowv[e];
    }
}

// xw = x @ W1.  4 waves/block, each wave handles 4 nodes; lane = output col.
// W1 (32 KB) stays L1-resident; x rows are wave-uniform broadcast float4 loads.
__global__ __launch_bounds__(256) void k_gemm1(const float* __restrict__ x,
                                               const float* __restrict__ W1,
                                               float* __restrict__ xw) {
    const int lane = threadIdx.x & 63;
    const int wave = threadIdx.x >> 6;
    const int n0 = (blockIdx.x * 4 + wave) * 4;             // 6250*16 = 100000 exact
    if (n0 >= N_NODES) return;
    float acc0 = 0.f, acc1 = 0.f, acc2 = 0.f, acc3 = 0.f;
    const float* xr0 = x + (size_t)(n0 + 0) * NFEAT;
    const float* xr1 = x + (size_t)(n0 + 1) * NFEAT;
    const float* xr2 = x + (size_t)(n0 + 2) * NFEAT;
    const float* xr3 = x + (size_t)(n0 + 3) * NFEAT;
    #pragma unroll
    for (int k = 0; k < NFEAT; k += 4) {
        float4 a0 = *(const float4*)&xr0[k];
        float4 a1 = *(const float4*)&xr1[k];
        float4 a2 = *(const float4*)&xr2[k];
        float4 a3 = *(const float4*)&xr3[k];
        float w0 = W1[(k + 0) * NHID + lane];
        float w1 = W1[(k + 1) * NHID + lane];
        float w2 = W1[(k + 2) * NHID + lane];
        float w3 = W1[(k + 3) * NHID + lane];
        acc0 += a0.x * w0 + a0.y * w1 + a0.z * w2 + a0.w * w3;
        acc1 += a1.x * w0 + a1.y * w1 + a1.z * w2 + a1.w * w3;
        acc2 += a2.x * w0 + a2.y * w1 + a2.z * w2 + a2.w * w3;
        acc3 += a3.x * w0 + a3.y * w1 + a3.z * w2 + a3.w * w3;
    }
    xw[(size_t)(n0 + 0) * NHID + lane] = acc0;
    xw[(size_t)(n0 + 1) * NHID + lane] = acc1;
    xw[(size_t)(n0 + 2) * NHID + lane] = acc2;
    xw[(size_t)(n0 + 3) * NHID + lane] = acc3;
}

// act1[n] = relu( dis[n]^2*xw[n] + sum_{r in N(n)} dis[n]*dis[r]*xw[r] + b1 )
// One wave per node, lane = feature. Neighbor index prefetched one iteration
// ahead to break the eidx-load -> xw-address dependency chain.
__global__ __launch_bounds__(256) void k_gather1(const float* __restrict__ xw,
                                                 const int* __restrict__ ptr,
                                                 const int* __restrict__ cnt,
                                                 const int* __restrict__ eidx,
                                                 const float* __restrict__ dis,
                                                 const float* __restrict__ b1,
                                                 float* __restrict__ act1) {
    const int lane = threadIdx.x & 63;
    const int wave = threadIdx.x >> 6;
    const int n = blockIdx.x * 4 + wave;
    if (n >= N_NODES) return;
    const float dn = dis[n];
    float acc = dn * dn * xw[(size_t)n * NHID + lane];      // self-loop
    const int p0 = ptr[n];
    const int c = cnt[n];
    if (c > 0) {
        int r = eidx[p0];
        for (int e = p0 + 1; e < p0 + c; ++e) {
            int rn = eidx[e];                               // prefetch next
            acc += dn * dis[r] * xw[(size_t)r * NHID + lane];
            r = rn;
        }
        acc += dn * dis[r] * xw[(size_t)r * NHID + lane];
    }
    act1[(size_t)n * NHID + lane] = fmaxf(acc + b1[lane], 0.f);
}

// xw2 = act1 @ W2.  One thread per (node, class); W2 (4 KB) L1-resident.
__global__ __launch_bounds__(256) void k_gemm2(const float* __restrict__ act1,
                                               const float* __restrict__ W2,
                                               float* __restrict__ xw2) {
    int tid = blockIdx.x * blockDim.x + threadIdx.x;
    if (tid >= N_NODES * NCLASS) return;
    int n = tid >> 4, cc = tid & 15;
    const float* ar = act1 + (size_t)n * NHID;
    float acc = 0.f;
    #pragma unroll
    for (int k = 0; k < NHID; k += 4) {
        float4 a = *(const float4*)&ar[k];
        acc += a.x * W2[(k + 0) * NCLASS + cc] + a.y * W2[(k + 1) * NCLASS + cc] +
               a.z * W2[(k + 2) * NCLASS + cc] + a.w * W2[(k + 3) * NCLASS + cc];
    }
    xw2[tid] = acc;
}

// Layer-2 aggregate + b2 + log_softmax fused. One wave per node; 4 lane-groups
// of 16 split the edge list, shfl_xor(16/32) reduces, 16-lane shuffles do
// the softmax max/sum.
__global__ __launch_bounds__(256) void k_gather2(const float* __restrict__ xw2,
                                                 const int* __restrict__ ptr,
                                                 const int* __restrict__ cnt,
                                                 const int* __restrict__ eidx,
                                                 const float* __restrict__ dis,
                                                 const float* __restrict__ b2,
                                                 float* __restrict__ out) {
    const int lane = threadIdx.x & 63;
    const int wave = threadIdx.x >> 6;
    const int n = blockIdx.x * 4 + wave;
    if (n >= N_NODES) return;
    const int f = lane & 15;
    const int g = lane >> 4;
    const float dn = dis[n];
    float acc = (g == 0) ? dn * dn * xw2[(size_t)n * NCLASS + f] : 0.f;
    const int p0 = ptr[n];
    const int c = cnt[n];
    for (int e = p0 + g; e < p0 + c; e += 4) {
        int r = eidx[e];
        acc += dn * dis[r] * xw2[(size_t)r * NCLASS + f];
    }
    acc += __shfl_xor(acc, 16);
    acc += __shfl_xor(acc, 32);                 // all lanes: full sum for f
    float v = acc + b2[f];
    float m = v;
    m = fmaxf(m, __shfl_xor(m, 1));
    m = fmaxf(m, __shfl_xor(m, 2));
    m = fmaxf(m, __shfl_xor(m, 4));
    m = fmaxf(m, __shfl_xor(m, 8));
    float ex = expf(v - m);
    float s = ex;
    s += __shfl_xor(s, 1);
    s += __shfl_xor(s, 2);
    s += __shfl_xor(s, 4);
    s += __shfl_xor(s, 8);
    float res = (v - m) - logf(s);
    if (lane < 16) out[(size_t)n * NCLASS + lane] = res;
}

// ---------------------------------------------------------------------------

static inline size_t align256(size_t x) { return (x + 255) & ~(size_t)255; }

extern "C" void kernel_launch(void* const* d_in, const int* in_sizes, int n_in,
                              void* d_out, int out_size, void* d_ws, size_t ws_size,
                              hipStream_t stream) {
    const float* x  = (const float*)d_in[0];
    const int*   ei = (const int*)d_in[1];        // [2, E] flat: row then col
    const float* W1 = (const float*)d_in[2];
    const float* b1 = (const float*)d_in[3];
    const float* W2 = (const float*)d_in[4];
    const float* b2 = (const float*)d_in[5];
    float* out = (float*)d_out;

    const int* rowv = ei;                         // edge_index[0] = sources
    const int* colv = ei + N_EDGES;               // edge_index[1] = targets

    char* ws = (char*)d_ws;
    size_t off = 0;
    int*   cnt    = (int*)(ws + off);  off = align256(off + sizeof(int)   * N_NODES);
    int*   ptr    = (int*)(ws + off);  off = align256(off + sizeof(int)   * N_NODES);
    int*   cursor = (int*)(ws + off);  off = align256(off + sizeof(int)   * N_NODES);
    int*   eidx   = (int*)(ws + off);  off = align256(off + sizeof(int)   * N_EDGES);
    float* dis    = (float*)(ws + off); off = align256(off + sizeof(float) * N_NODES);
    float* xw     = (float*)(ws + off); off = align256(off + sizeof(float) * N_NODES * NHID);
    float* act1   = (float*)(ws + off); off = align256(off + sizeof(float) * N_NODES * NHID);
    float* xw2    = (float*)(ws + off); off = align256(off + sizeof(float) * N_NODES * NCLASS);
    (void)ws_size; (void)n_in; (void)in_sizes; (void)out_size;

    // 1. degree count
    k_zero_cnt<<<512, 256, 0, stream>>>(cnt);
    k_count<<<2048, 256, 0, stream>>>(colv, cnt);
    // 2. prefix scan -> ptr/cursor, dis
    k_scan<<<1, 1024, 0, stream>>>(cnt, ptr, cursor, dis);
    // 3. CSR fill (shared by both layers)
    k_fill<<<2048, 256, 0, stream>>>(rowv, colv, cursor, eidx);
    // 4. layer-1 transform
    k_gemm1<<<N_NODES / 16, 256, 0, stream>>>(x, W1, xw);
    // 5. layer-1 aggregate + bias + relu
    k_gather1<<<(N_NODES + 3) / 4, 256, 0, stream>>>(xw, ptr, cnt, eidx, dis, b1, act1);
    // 6. layer-2 transform
    k_gemm2<<<(N_NODES * NCLASS + 255) / 256, 256, 0, stream>>>(act1, W2, xw2);
    // 7. layer-2 aggregate + bias + log_softmax
    k_gather2<<<(N_NODES + 3) / 4, 256, 0, stream>>>(xw2, ptr, cnt, eidx, dis, b2, out);
}

// Round 5
// 578.993 us; speedup vs baseline: 1.5010x; 1.5010x over previous
//
#include <hip/hip_runtime.h>
#include <math.h>

#define N_NODES 100000
#define N_EDGES 1600000
#define NFEAT   128
#define NHID    64
#define NCLASS  16

#define SCAN_NB 391                 // ceil(100000 / 256)

// ---------------------------------------------------------------------------
// Pipeline:  degree-count -> multi-block scan (CSR ptr + deg^{-1/2}) ->
//            CSR fill -> [L1] gemm1 -> gather1 (+bias+relu) ->
//            [L2] gemm2 -> gather2 (+bias+log_softmax)
// No float atomics: aggregation is gather-based over a counting-sort CSR
// built once and reused by both layers.
//
// Workspace (256B-aligned), ~66 MiB:
//   cnt int[N] | ptr int[N] | cursor int[N] | eidx int[E] | dis f32[N]
//   bsum int[512] | bbase int[512] | xw f32[N*64] | act1 f32[N*64] | xw2 f32[N*16]
// ---------------------------------------------------------------------------

__global__ void k_zero_cnt(int* __restrict__ cnt) {
    for (int i = blockIdx.x * blockDim.x + threadIdx.x; i < N_NODES;
         i += gridDim.x * blockDim.x)
        cnt[i] = 0;
}

__global__ void k_count(const int* __restrict__ colv, int* __restrict__ cnt) {
    for (int e = blockIdx.x * blockDim.x + threadIdx.x; e < N_EDGES;
         e += gridDim.x * blockDim.x)
        atomicAdd(&cnt[colv[e]], 1);
}

// --- multi-block exclusive scan of cnt[] -> ptr/cursor, dis = rsqrt(cnt+1) ---
// Phase 1: per-block (256 nodes) sums.
__global__ __launch_bounds__(256) void k_scan_partial(const int* __restrict__ cnt,
                                                      int* __restrict__ bsum) {
    __shared__ int sh[256];
    const int t = threadIdx.x;
    const int i = blockIdx.x * 256 + t;
    int v = (i < N_NODES) ? cnt[i] : 0;
    sh[t] = v;
    __syncthreads();
    for (int off = 128; off > 0; off >>= 1) {
        if (t < off) sh[t] += sh[t + off];
        __syncthreads();
    }
    if (t == 0) bsum[blockIdx.x] = sh[0];
}

// Phase 2: one block scans the 391 block sums -> exclusive block bases.
__global__ __launch_bounds__(512) void k_scan_bases(const int* __restrict__ bsum,
                                                    int* __restrict__ bbase) {
    __shared__ int sh[512];
    const int t = threadIdx.x;
    int v = (t < SCAN_NB) ? bsum[t] : 0;
    sh[t] = v;
    __syncthreads();
    for (int off = 1; off < 512; off <<= 1) {
        int u = (t >= off) ? sh[t - off] : 0;
        __syncthreads();
        sh[t] += u;
        __syncthreads();
    }
    if (t < SCAN_NB) bbase[t] = sh[t] - v;          // exclusive
}

// Phase 3: block-local exclusive scan + block base -> ptr/cursor/dis.
__global__ __launch_bounds__(256) void k_scan_apply(const int* __restrict__ cnt,
                                                    const int* __restrict__ bbase,
                                                    int* __restrict__ ptr,
                                                    int* __restrict__ cursor,
                                                    float* __restrict__ dis) {
    __shared__ int sh[256];
    const int t = threadIdx.x;
    const int i = blockIdx.x * 256 + t;
    int v = (i < N_NODES) ? cnt[i] : 0;
    sh[t] = v;
    __syncthreads();
    for (int off = 1; off < 256; off <<= 1) {
        int u = (t >= off) ? sh[t - off] : 0;
        __syncthreads();
        sh[t] += u;
        __syncthreads();
    }
    if (i < N_NODES) {
        int base = bbase[blockIdx.x] + sh[t] - v;   // exclusive prefix
        ptr[i] = base;
        cursor[i] = base;
        dis[i] = rsqrtf((float)(v + 1));            // +1 = self-loop
    }
}

__global__ void k_fill(const int* __restrict__ rowv, const int* __restrict__ colv,
                       int* __restrict__ cursor, int* __restrict__ eidx) {
    for (int e = blockIdx.x * blockDim.x + threadIdx.x; e < N_EDGES;
         e += gridDim.x * blockDim.x) {
        int c = colv[e];
        int p = atomicAdd(&cursor[c], 1);
        eidx[p] = rowv[e];
    }
}

// xw = x @ W1.  4 waves/block, each wave handles 4 nodes; lane = output col.
// W1 (32 KB) stays L1-resident; x rows are wave-uniform broadcast float4 loads.
__global__ __launch_bounds__(256) void k_gemm1(const float* __restrict__ x,
                                               const float* __restrict__ W1,
                                               float* __restrict__ xw) {
    const int lane = threadIdx.x & 63;
    const int wave = threadIdx.x >> 6;
    const int n0 = (blockIdx.x * 4 + wave) * 4;             // 6250*16 = 100000 exact
    if (n0 >= N_NODES) return;
    float acc0 = 0.f, acc1 = 0.f, acc2 = 0.f, acc3 = 0.f;
    const float* xr0 = x + (size_t)(n0 + 0) * NFEAT;
    const float* xr1 = x + (size_t)(n0 + 1) * NFEAT;
    const float* xr2 = x + (size_t)(n0 + 2) * NFEAT;
    const float* xr3 = x + (size_t)(n0 + 3) * NFEAT;
    #pragma unroll
    for (int k = 0; k < NFEAT; k += 4) {
        float4 a0 = *(const float4*)&xr0[k];
        float4 a1 = *(const float4*)&xr1[k];
        float4 a2 = *(const float4*)&xr2[k];
        float4 a3 = *(const float4*)&xr3[k];
        float w0 = W1[(k + 0) * NHID + lane];
        float w1 = W1[(k + 1) * NHID + lane];
        float w2 = W1[(k + 2) * NHID + lane];
        float w3 = W1[(k + 3) * NHID + lane];
        acc0 += a0.x * w0 + a0.y * w1 + a0.z * w2 + a0.w * w3;
        acc1 += a1.x * w0 + a1.y * w1 + a1.z * w2 + a1.w * w3;
        acc2 += a2.x * w0 + a2.y * w1 + a2.z * w2 + a2.w * w3;
        acc3 += a3.x * w0 + a3.y * w1 + a3.z * w2 + a3.w * w3;
    }
    xw[(size_t)(n0 + 0) * NHID + lane] = acc0;
    xw[(size_t)(n0 + 1) * NHID + lane] = acc1;
    xw[(size_t)(n0 + 2) * NHID + lane] = acc2;
    xw[(size_t)(n0 + 3) * NHID + lane] = acc3;
}

// act1[n] = relu( dis[n]^2*xw[n] + dn * sum_{r} dis[r]*xw[r] + b1 )
// One wave per node, lane = feature. 4-way unroll with independent
// accumulators keeps 4 gather loads in flight (latency-bound at deg~16).
__global__ __launch_bounds__(256) void k_gather1(const float* __restrict__ xw,
                                                 const int* __restrict__ ptr,
                                                 const int* __restrict__ cnt,
                                                 const int* __restrict__ eidx,
                                                 const float* __restrict__ dis,
                                                 const float* __restrict__ b1,
                                                 float* __restrict__ act1) {
    const int lane = threadIdx.x & 63;
    const int wave = threadIdx.x >> 6;
    const int n = blockIdx.x * 4 + wave;
    if (n >= N_NODES) return;
    const float dn = dis[n];
    const int p0 = ptr[n];
    const int pend = p0 + cnt[n];
    float a0 = 0.f, a1 = 0.f, a2 = 0.f, a3 = 0.f;
    int e = p0;
    for (; e + 4 <= pend; e += 4) {
        int r0 = eidx[e + 0], r1 = eidx[e + 1], r2 = eidx[e + 2], r3 = eidx[e + 3];
        a0 += dis[r0] * xw[(size_t)r0 * NHID + lane];
        a1 += dis[r1] * xw[(size_t)r1 * NHID + lane];
        a2 += dis[r2] * xw[(size_t)r2 * NHID + lane];
        a3 += dis[r3] * xw[(size_t)r3 * NHID + lane];
    }
    for (; e < pend; ++e) {
        int r = eidx[e];
        a0 += dis[r] * xw[(size_t)r * NHID + lane];
    }
    float acc = dn * dn * xw[(size_t)n * NHID + lane] + dn * ((a0 + a1) + (a2 + a3));
    act1[(size_t)n * NHID + lane] = fmaxf(acc + b1[lane], 0.f);
}

// xw2 = act1 @ W2.  One thread per (node, class); W2 (4 KB) L1-resident.
__global__ __launch_bounds__(256) void k_gemm2(const float* __restrict__ act1,
                                               const float* __restrict__ W2,
                                               float* __restrict__ xw2) {
    int tid = blockIdx.x * blockDim.x + threadIdx.x;
    if (tid >= N_NODES * NCLASS) return;
    int n = tid >> 4, cc = tid & 15;
    const float* ar = act1 + (size_t)n * NHID;
    float acc = 0.f;
    #pragma unroll
    for (int k = 0; k < NHID; k += 4) {
        float4 a = *(const float4*)&ar[k];
        acc += a.x * W2[(k + 0) * NCLASS + cc] + a.y * W2[(k + 1) * NCLASS + cc] +
               a.z * W2[(k + 2) * NCLASS + cc] + a.w * W2[(k + 3) * NCLASS + cc];
    }
    xw2[tid] = acc;
}

// Layer-2 aggregate + b2 + log_softmax fused. One wave per node; 4 lane-groups
// of 16 split the edge list, shfl_xor(16/32) reduces, 16-lane shuffles do
// the softmax max/sum.
__global__ __launch_bounds__(256) void k_gather2(const float* __restrict__ xw2,
                                                 const int* __restrict__ ptr,
                                                 const int* __restrict__ cnt,
                                                 const int* __restrict__ eidx,
                                                 const float* __restrict__ dis,
                                                 const float* __restrict__ b2,
                                                 float* __restrict__ out) {
    const int lane = threadIdx.x & 63;
    const int wave = threadIdx.x >> 6;
    const int n = blockIdx.x * 4 + wave;
    if (n >= N_NODES) return;
    const int f = lane & 15;
    const int g = lane >> 4;
    const float dn = dis[n];
    float acc = (g == 0) ? dn * dn * xw2[(size_t)n * NCLASS + f] : 0.f;
    const int p0 = ptr[n];
    const int c = cnt[n];
    for (int e = p0 + g; e < p0 + c; e += 4) {
        int r = eidx[e];
        acc += dn * dis[r] * xw2[(size_t)r * NCLASS + f];
    }
    acc += __shfl_xor(acc, 16);
    acc += __shfl_xor(acc, 32);                 // all lanes: full sum for f
    float v = acc + b2[f];
    float m = v;
    m = fmaxf(m, __shfl_xor(m, 1));
    m = fmaxf(m, __shfl_xor(m, 2));
    m = fmaxf(m, __shfl_xor(m, 4));
    m = fmaxf(m, __shfl_xor(m, 8));
    float ex = expf(v - m);
    float s = ex;
    s += __shfl_xor(s, 1);
    s += __shfl_xor(s, 2);
    s += __shfl_xor(s, 4);
    s += __shfl_xor(s, 8);
    float res = (v - m) - logf(s);
    if (lane < 16) out[(size_t)n * NCLASS + lane] = res;
}

// ---------------------------------------------------------------------------

static inline size_t align256(size_t x) { return (x + 255) & ~(size_t)255; }

extern "C" void kernel_launch(void* const* d_in, const int* in_sizes, int n_in,
                              void* d_out, int out_size, void* d_ws, size_t ws_size,
                              hipStream_t stream) {
    const float* x  = (const float*)d_in[0];
    const int*   ei = (const int*)d_in[1];        // [2, E] flat: row then col
    const float* W1 = (const float*)d_in[2];
    const float* b1 = (const float*)d_in[3];
    const float* W2 = (const float*)d_in[4];
    const float* b2 = (const float*)d_in[5];
    float* out = (float*)d_out;

    const int* rowv = ei;                         // edge_index[0] = sources
    const int* colv = ei + N_EDGES;               // edge_index[1] = targets

    char* ws = (char*)d_ws;
    size_t off = 0;
    int*   cnt    = (int*)(ws + off);  off = align256(off + sizeof(int)   * N_NODES);
    int*   ptr    = (int*)(ws + off);  off = align256(off + sizeof(int)   * N_NODES);
    int*   cursor = (int*)(ws + off);  off = align256(off + sizeof(int)   * N_NODES);
    int*   eidx   = (int*)(ws + off);  off = align256(off + sizeof(int)   * N_EDGES);
    float* dis    = (float*)(ws + off); off = align256(off + sizeof(float) * N_NODES);
    int*   bsum   = (int*)(ws + off);  off = align256(off + sizeof(int)   * 512);
    int*   bbase  = (int*)(ws + off);  off = align256(off + sizeof(int)   * 512);
    float* xw     = (float*)(ws + off); off = align256(off + sizeof(float) * N_NODES * NHID);
    float* act1   = (float*)(ws + off); off = align256(off + sizeof(float) * N_NODES * NHID);
    float* xw2    = (float*)(ws + off); off = align256(off + sizeof(float) * N_NODES * NCLASS);
    (void)ws_size; (void)n_in; (void)in_sizes; (void)out_size;

    // 1. degree count
    k_zero_cnt<<<512, 256, 0, stream>>>(cnt);
    k_count<<<2048, 256, 0, stream>>>(colv, cnt);
    // 2. multi-block prefix scan -> ptr/cursor, dis
    k_scan_partial<<<SCAN_NB, 256, 0, stream>>>(cnt, bsum);
    k_scan_bases<<<1, 512, 0, stream>>>(bsum, bbase);
    k_scan_apply<<<SCAN_NB, 256, 0, stream>>>(cnt, bbase, ptr, cursor, dis);
    // 3. CSR fill (shared by both layers)
    k_fill<<<2048, 256, 0, stream>>>(rowv, colv, cursor, eidx);
    // 4. layer-1 transform
    k_gemm1<<<N_NODES / 16, 256, 0, stream>>>(x, W1, xw);
    // 5. layer-1 aggregate + bias + relu
    k_gather1<<<(N_NODES + 3) / 4, 256, 0, stream>>>(xw, ptr, cnt, eidx, dis, b1, act1);
    // 6. layer-2 transform
    k_gemm2<<<(N_NODES * NCLASS + 255) / 256, 256, 0, stream>>>(act1, W2, xw2);
    // 7. layer-2 aggregate + bias + log_softmax
    k_gather2<<<(N_NODES + 3) / 4, 256, 0, stream>>>(xw2, ptr, cnt, eidx, dis, b2, out);
}

// Round 6
// 440.211 us; speedup vs baseline: 1.9742x; 1.3153x over previous
//
#include <hip/hip_runtime.h>
#include <math.h>

#define N_NODES 100000
#define N_EDGES 1600000
#define NFEAT   128
#define NHID    64
#define NCLASS  16

#define SCAN_NB 391                 // ceil(100000 / 256)
#define NPART   8                   // XCD count; 100000 = 8 * 12500
#define PART_SZ (N_NODES / NPART)

// ---------------------------------------------------------------------------
// Pipeline:  degree-count -> multi-block scan (CSR ptr + deg^{-1/2}) ->
//            XCD-partitioned CSR fill -> [L1] LDS-tiled gemm1 ->
//            gather1 (+bias+relu) -> [L2] gemm2 -> gather2 (+log_softmax)
// ---------------------------------------------------------------------------

__global__ void k_zero_cnt(int* __restrict__ cnt) {
    for (int i = blockIdx.x * blockDim.x + threadIdx.x; i < N_NODES;
         i += gridDim.x * blockDim.x)
        cnt[i] = 0;
}

__global__ void k_count(const int* __restrict__ colv, int* __restrict__ cnt) {
    for (int e = blockIdx.x * blockDim.x + threadIdx.x; e < N_EDGES;
         e += gridDim.x * blockDim.x)
        atomicAdd(&cnt[colv[e]], 1);
}

// --- multi-block exclusive scan of cnt[] -> ptr/cursor, dis = rsqrt(cnt+1) ---
__global__ __launch_bounds__(256) void k_scan_partial(const int* __restrict__ cnt,
                                                      int* __restrict__ bsum) {
    __shared__ int sh[256];
    const int t = threadIdx.x;
    const int i = blockIdx.x * 256 + t;
    int v = (i < N_NODES) ? cnt[i] : 0;
    sh[t] = v;
    __syncthreads();
    for (int off = 128; off > 0; off >>= 1) {
        if (t < off) sh[t] += sh[t + off];
        __syncthreads();
    }
    if (t == 0) bsum[blockIdx.x] = sh[0];
}

__global__ __launch_bounds__(512) void k_scan_bases(const int* __restrict__ bsum,
                                                    int* __restrict__ bbase) {
    __shared__ int sh[512];
    const int t = threadIdx.x;
    int v = (t < SCAN_NB) ? bsum[t] : 0;
    sh[t] = v;
    __syncthreads();
    for (int off = 1; off < 512; off <<= 1) {
        int u = (t >= off) ? sh[t - off] : 0;
        __syncthreads();
        sh[t] += u;
        __syncthreads();
    }
    if (t < SCAN_NB) bbase[t] = sh[t] - v;          // exclusive
}

__global__ __launch_bounds__(256) void k_scan_apply(const int* __restrict__ cnt,
                                                    const int* __restrict__ bbase,
                                                    int* __restrict__ ptr,
                                                    int* __restrict__ cursor,
                                                    float* __restrict__ dis) {
    __shared__ int sh[256];
    const int t = threadIdx.x;
    const int i = blockIdx.x * 256 + t;
    int v = (i < N_NODES) ? cnt[i] : 0;
    sh[t] = v;
    __syncthreads();
    for (int off = 1; off < 256; off <<= 1) {
        int u = (t >= off) ? sh[t - off] : 0;
        __syncthreads();
        sh[t] += u;
        __syncthreads();
    }
    if (i < N_NODES) {
        int base = bbase[blockIdx.x] + sh[t] - v;   // exclusive prefix
        ptr[i] = base;
        cursor[i] = base;
        dis[i] = rsqrtf((float)(v + 1));            // +1 = self-loop
    }
}

// XCD-partitioned CSR fill. part = blockIdx.x & 7: with default round-robin
// dispatch, all blocks of one partition sit on one XCD, so the ~800 KB eidx
// window for that partition stays resident in that XCD's L2 and every line
// accumulates all its slots before one full-line writeback (fixes the 16x
// write amplification: WRITE_SIZE was 107 MB for a 6.4 MB array).
// Correctness does NOT depend on the XCD mapping -- any dispatch order works.
__global__ void k_fill(const int* __restrict__ rowv, const int* __restrict__ colv,
                       int* __restrict__ cursor, int* __restrict__ eidx) {
    const int part = blockIdx.x & (NPART - 1);
    const int lo = part * PART_SZ;
    const int hi = lo + PART_SZ;
    const int nb = gridDim.x >> 3;                 // blocks per partition
    const int bi = blockIdx.x >> 3;
    for (int e = bi * blockDim.x + threadIdx.x; e < N_EDGES;
         e += nb * blockDim.x) {
        int c = colv[e];
        if (c >= lo && c < hi) {
            int p = atomicAdd(&cursor[c], 1);
            eidx[p] = rowv[e];
        }
    }
}

// xw = x @ W1, LDS-tiled. Block tile: 64 nodes x 64 cols, K=128 fully staged.
// x tile 64x128 and W1^T 64x128 in padded LDS (stride 132 floats: b128-aligned,
// worst bank aliasing 2-way = free). Thread (tx=t&15, ty=t>>4) computes a
// 4-node x 4-col register tile; cols strided by 16 to keep ws reads 2-way max.
#define XS_LD 132
#define WS_LD 132
__global__ __launch_bounds__(256) void k_gemm1(const float* __restrict__ x,
                                               const float* __restrict__ W1,
                                               float* __restrict__ xw) {
    __shared__ float xs[64 * XS_LD];
    __shared__ float ws[64 * WS_LD];
    const int t = threadIdx.x;
    const int bm = blockIdx.x * 64;                // node base (last block ragged)

    // stage x[bm..bm+63][0..127] -> xs (coalesced float4 stream)
    #pragma unroll
    for (int it = 0; it < 8; ++it) {
        int f = 4 * (t + 256 * it);                // flat float index in 64x128
        int r = f >> 7, k = f & 127;
        float4 v = make_float4(0.f, 0.f, 0.f, 0.f);
        if (bm + r < N_NODES) v = *(const float4*)&x[(size_t)(bm + r) * NFEAT + k];
        *(float4*)&xs[r * XS_LD + k] = v;
    }
    // stage W1[128][64] transposed -> ws[col][k]
    #pragma unroll
    for (int it = 0; it < 8; ++it) {
        int f = 4 * (t + 256 * it);                // flat float index in 128x64
        int k = f >> 6, c = f & 63;
        float4 v = *(const float4*)&W1[f];
        ws[(c + 0) * WS_LD + k] = v.x;
        ws[(c + 1) * WS_LD + k] = v.y;
        ws[(c + 2) * WS_LD + k] = v.z;
        ws[(c + 3) * WS_LD + k] = v.w;
    }
    __syncthreads();

    const int tx = t & 15, ty = t >> 4;
    float acc[4][4];
    #pragma unroll
    for (int i = 0; i < 4; ++i)
        #pragma unroll
        for (int j = 0; j < 4; ++j) acc[i][j] = 0.f;

    for (int k0 = 0; k0 < NFEAT; k0 += 4) {
        float4 a[4], b[4];
        #pragma unroll
        for (int i = 0; i < 4; ++i)
            a[i] = *(const float4*)&xs[(4 * ty + i) * XS_LD + k0];
        #pragma unroll
        for (int j = 0; j < 4; ++j)
            b[j] = *(const float4*)&ws[(tx + 16 * j) * WS_LD + k0];
        #pragma unroll
        for (int i = 0; i < 4; ++i)
            #pragma unroll
            for (int j = 0; j < 4; ++j)
                acc[i][j] += a[i].x * b[j].x + a[i].y * b[j].y +
                             a[i].z * b[j].z + a[i].w * b[j].w;
    }

    #pragma unroll
    for (int i = 0; i < 4; ++i) {
        int n = bm + 4 * ty + i;
        if (n < N_NODES) {
            #pragma unroll
            for (int j = 0; j < 4; ++j)
                xw[(size_t)n * NHID + tx + 16 * j] = acc[i][j];
        }
    }
}

// act1[n] = relu( dis[n]^2*xw[n] + dn * sum_{r} dis[r]*xw[r] + b1 )
__global__ __launch_bounds__(256) void k_gather1(const float* __restrict__ xw,
                                                 const int* __restrict__ ptr,
                                                 const int* __restrict__ cnt,
                                                 const int* __restrict__ eidx,
                                                 const float* __restrict__ dis,
                                                 const float* __restrict__ b1,
                                                 float* __restrict__ act1) {
    const int lane = threadIdx.x & 63;
    const int wave = threadIdx.x >> 6;
    const int n = blockIdx.x * 4 + wave;
    if (n >= N_NODES) return;
    const float dn = dis[n];
    const int p0 = ptr[n];
    const int pend = p0 + cnt[n];
    float a0 = 0.f, a1 = 0.f, a2 = 0.f, a3 = 0.f;
    int e = p0;
    for (; e + 4 <= pend; e += 4) {
        int r0 = eidx[e + 0], r1 = eidx[e + 1], r2 = eidx[e + 2], r3 = eidx[e + 3];
        a0 += dis[r0] * xw[(size_t)r0 * NHID + lane];
        a1 += dis[r1] * xw[(size_t)r1 * NHID + lane];
        a2 += dis[r2] * xw[(size_t)r2 * NHID + lane];
        a3 += dis[r3] * xw[(size_t)r3 * NHID + lane];
    }
    for (; e < pend; ++e) {
        int r = eidx[e];
        a0 += dis[r] * xw[(size_t)r * NHID + lane];
    }
    float acc = dn * dn * xw[(size_t)n * NHID + lane] + dn * ((a0 + a1) + (a2 + a3));
    act1[(size_t)n * NHID + lane] = fmaxf(acc + b1[lane], 0.f);
}

// xw2 = act1 @ W2.  One thread per (node, class); W2 (4 KB) L1-resident.
__global__ __launch_bounds__(256) void k_gemm2(const float* __restrict__ act1,
                                               const float* __restrict__ W2,
                                               float* __restrict__ xw2) {
    int tid = blockIdx.x * blockDim.x + threadIdx.x;
    if (tid >= N_NODES * NCLASS) return;
    int n = tid >> 4, cc = tid & 15;
    const float* ar = act1 + (size_t)n * NHID;
    float acc = 0.f;
    #pragma unroll
    for (int k = 0; k < NHID; k += 4) {
        float4 a = *(const float4*)&ar[k];
        acc += a.x * W2[(k + 0) * NCLASS + cc] + a.y * W2[(k + 1) * NCLASS + cc] +
               a.z * W2[(k + 2) * NCLASS + cc] + a.w * W2[(k + 3) * NCLASS + cc];
    }
    xw2[tid] = acc;
}

// Layer-2 aggregate + b2 + log_softmax fused.
__global__ __launch_bounds__(256) void k_gather2(const float* __restrict__ xw2,
                                                 const int* __restrict__ ptr,
                                                 const int* __restrict__ cnt,
                                                 const int* __restrict__ eidx,
                                                 const float* __restrict__ dis,
                                                 const float* __restrict__ b2,
                                                 float* __restrict__ out) {
    const int lane = threadIdx.x & 63;
    const int wave = threadIdx.x >> 6;
    const int n = blockIdx.x * 4 + wave;
    if (n >= N_NODES) return;
    const int f = lane & 15;
    const int g = lane >> 4;
    const float dn = dis[n];
    float acc = (g == 0) ? dn * dn * xw2[(size_t)n * NCLASS + f] : 0.f;
    const int p0 = ptr[n];
    const int c = cnt[n];
    for (int e = p0 + g; e < p0 + c; e += 4) {
        int r = eidx[e];
        acc += dn * dis[r] * xw2[(size_t)r * NCLASS + f];
    }
    acc += __shfl_xor(acc, 16);
    acc += __shfl_xor(acc, 32);
    float v = acc + b2[f];
    float m = v;
    m = fmaxf(m, __shfl_xor(m, 1));
    m = fmaxf(m, __shfl_xor(m, 2));
    m = fmaxf(m, __shfl_xor(m, 4));
    m = fmaxf(m, __shfl_xor(m, 8));
    float ex = expf(v - m);
    float s = ex;
    s += __shfl_xor(s, 1);
    s += __shfl_xor(s, 2);
    s += __shfl_xor(s, 4);
    s += __shfl_xor(s, 8);
    float res = (v - m) - logf(s);
    if (lane < 16) out[(size_t)n * NCLASS + lane] = res;
}

// ---------------------------------------------------------------------------

static inline size_t align256(size_t x) { return (x + 255) & ~(size_t)255; }

extern "C" void kernel_launch(void* const* d_in, const int* in_sizes, int n_in,
                              void* d_out, int out_size, void* d_ws, size_t ws_size,
                              hipStream_t stream) {
    const float* x  = (const float*)d_in[0];
    const int*   ei = (const int*)d_in[1];        // [2, E] flat: row then col
    const float* W1 = (const float*)d_in[2];
    const float* b1 = (const float*)d_in[3];
    const float* W2 = (const float*)d_in[4];
    const float* b2 = (const float*)d_in[5];
    float* out = (float*)d_out;

    const int* rowv = ei;                         // edge_index[0] = sources
    const int* colv = ei + N_EDGES;               // edge_index[1] = targets

    char* ws = (char*)d_ws;
    size_t off = 0;
    int*   cnt    = (int*)(ws + off);  off = align256(off + sizeof(int)   * N_NODES);
    int*   ptr    = (int*)(ws + off);  off = align256(off + sizeof(int)   * N_NODES);
    int*   cursor = (int*)(ws + off);  off = align256(off + sizeof(int)   * N_NODES);
    int*   eidx   = (int*)(ws + off);  off = align256(off + sizeof(int)   * N_EDGES);
    float* dis    = (float*)(ws + off); off = align256(off + sizeof(float) * N_NODES);
    int*   bsum   = (int*)(ws + off);  off = align256(off + sizeof(int)   * 512);
    int*   bbase  = (int*)(ws + off);  off = align256(off + sizeof(int)   * 512);
    float* xw     = (float*)(ws + off); off = align256(off + sizeof(float) * N_NODES * NHID);
    float* act1   = (float*)(ws + off); off = align256(off + sizeof(float) * N_NODES * NHID);
    float* xw2    = (float*)(ws + off); off = align256(off + sizeof(float) * N_NODES * NCLASS);
    (void)ws_size; (void)n_in; (void)in_sizes; (void)out_size;

    // 1. degree count
    k_zero_cnt<<<512, 256, 0, stream>>>(cnt);
    k_count<<<2048, 256, 0, stream>>>(colv, cnt);
    // 2. multi-block prefix scan -> ptr/cursor, dis
    k_scan_partial<<<SCAN_NB, 256, 0, stream>>>(cnt, bsum);
    k_scan_bases<<<1, 512, 0, stream>>>(bsum, bbase);
    k_scan_apply<<<SCAN_NB, 256, 0, stream>>>(cnt, bbase, ptr, cursor, dis);
    // 3. XCD-partitioned CSR fill
    k_fill<<<2048, 256, 0, stream>>>(rowv, colv, cursor, eidx);
    // 4. layer-1 transform (LDS-tiled GEMM)
    k_gemm1<<<(N_NODES + 63) / 64, 256, 0, stream>>>(x, W1, xw);
    // 5. layer-1 aggregate + bias + relu
    k_gather1<<<(N_NODES + 3) / 4, 256, 0, stream>>>(xw, ptr, cnt, eidx, dis, b1, act1);
    // 6. layer-2 transform
    k_gemm2<<<(N_NODES * NCLASS + 255) / 256, 256, 0, stream>>>(act1, W2, xw2);
    // 7. layer-2 aggregate + bias + log_softmax
    k_gather2<<<(N_NODES + 3) / 4, 256, 0, stream>>>(xw2, ptr, cnt, eidx, dis, b2, out);
}

// Round 8
// 429.589 us; speedup vs baseline: 2.0231x; 1.0247x over previous
//
#include <hip/hip_runtime.h>
#include <hip/hip_bf16.h>
#include <math.h>

#define N_NODES 100000
#define N_EDGES 1600000
#define NFEAT   128
#define NHID    64
#define NCLASS  16

#define SCAN_NB 391                 // ceil(100000 / 256)
#define NPART   8                   // XCD count; 100000 = 8 * 12500
#define PART_SZ (N_NODES / NPART)

// ---------------------------------------------------------------------------
// Pipeline:  degree-count -> multi-block scan (CSR ptr + deg^{-1/2}) ->
//            XCD-partitioned CSR fill -> [L1] LDS-tiled gemm1 (epilogue:
//            sxw = bf16(dis*xw)) -> gather1 over bf16 sxw (+bias+relu) ->
//            [L2] gemm2 -> gather2 (+log_softmax)
// gather1 traffic analysis (R6 counters): fp32 table hit the compulsory
// per-XCD L2-duplication floor (8 x 25.6 MB ~ 196 MB FETCH). bf16 halves the
// table to 12.8 MB -> ~halves the floor. Pre-scaling by dis[r] removes the
// per-edge random dis lookup.
// ---------------------------------------------------------------------------

__global__ void k_zero_cnt(int* __restrict__ cnt) {
    for (int i = blockIdx.x * blockDim.x + threadIdx.x; i < N_NODES;
         i += gridDim.x * blockDim.x)
        cnt[i] = 0;
}

__global__ void k_count(const int* __restrict__ colv, int* __restrict__ cnt) {
    for (int e = blockIdx.x * blockDim.x + threadIdx.x; e < N_EDGES;
         e += gridDim.x * blockDim.x)
        atomicAdd(&cnt[colv[e]], 1);
}

// --- multi-block exclusive scan of cnt[] -> ptr/cursor, dis = rsqrt(cnt+1) ---
__global__ __launch_bounds__(256) void k_scan_partial(const int* __restrict__ cnt,
                                                      int* __restrict__ bsum) {
    __shared__ int sh[256];
    const int t = threadIdx.x;
    const int i = blockIdx.x * 256 + t;
    int v = (i < N_NODES) ? cnt[i] : 0;
    sh[t] = v;
    __syncthreads();
    for (int off = 128; off > 0; off >>= 1) {
        if (t < off) sh[t] += sh[t + off];
        __syncthreads();
    }
    if (t == 0) bsum[blockIdx.x] = sh[0];
}

__global__ __launch_bounds__(512) void k_scan_bases(const int* __restrict__ bsum,
                                                    int* __restrict__ bbase) {
    __shared__ int sh[512];
    const int t = threadIdx.x;
    int v = (t < SCAN_NB) ? bsum[t] : 0;
    sh[t] = v;
    __syncthreads();
    for (int off = 1; off < 512; off <<= 1) {
        int u = (t >= off) ? sh[t - off] : 0;
        __syncthreads();
        sh[t] += u;
        __syncthreads();
    }
    if (t < SCAN_NB) bbase[t] = sh[t] - v;          // exclusive
}

__global__ __launch_bounds__(256) void k_scan_apply(const int* __restrict__ cnt,
                                                    const int* __restrict__ bbase,
                                                    int* __restrict__ ptr,
                                                    int* __restrict__ cursor,
                                                    float* __restrict__ dis) {
    __shared__ int sh[256];
    const int t = threadIdx.x;
    const int i = blockIdx.x * 256 + t;
    int v = (i < N_NODES) ? cnt[i] : 0;
    sh[t] = v;
    __syncthreads();
    for (int off = 1; off < 256; off <<= 1) {
        int u = (t >= off) ? sh[t - off] : 0;
        __syncthreads();
        sh[t] += u;
        __syncthreads();
    }
    if (i < N_NODES) {
        int base = bbase[blockIdx.x] + sh[t] - v;   // exclusive prefix
        ptr[i] = base;
        cursor[i] = base;
        dis[i] = rsqrtf((float)(v + 1));            // +1 = self-loop
    }
}

// XCD-partitioned CSR fill (fixes 16x write amplification; see R5 notes).
__global__ void k_fill(const int* __restrict__ rowv, const int* __restrict__ colv,
                       int* __restrict__ cursor, int* __restrict__ eidx) {
    const int part = blockIdx.x & (NPART - 1);
    const int lo = part * PART_SZ;
    const int hi = lo + PART_SZ;
    const int nb = gridDim.x >> 3;                 // blocks per partition
    const int bi = blockIdx.x >> 3;
    for (int e = bi * blockDim.x + threadIdx.x; e < N_EDGES;
         e += nb * blockDim.x) {
        int c = colv[e];
        if (c >= lo && c < hi) {
            int p = atomicAdd(&cursor[c], 1);
            eidx[p] = rowv[e];
        }
    }
}

// xw = x @ W1, LDS-tiled (64x64 tile, K=128). Epilogue scales each output row
// by dis[n] and stores bf16 -> sxw (the gather table).
#define XS_LD 132
#define WS_LD 132
__global__ __launch_bounds__(256) void k_gemm1(const float* __restrict__ x,
                                               const float* __restrict__ W1,
                                               const float* __restrict__ dis,
                                               __hip_bfloat16* __restrict__ sxw) {
    __shared__ float xs[64 * XS_LD];
    __shared__ float ws[64 * WS_LD];
    const int t = threadIdx.x;
    const int bm = blockIdx.x * 64;                // node base (last block ragged)

    #pragma unroll
    for (int it = 0; it < 8; ++it) {
        int f = 4 * (t + 256 * it);                // flat float index in 64x128
        int r = f >> 7, k = f & 127;
        float4 v = make_float4(0.f, 0.f, 0.f, 0.f);
        if (bm + r < N_NODES) v = *(const float4*)&x[(size_t)(bm + r) * NFEAT + k];
        *(float4*)&xs[r * XS_LD + k] = v;
    }
    #pragma unroll
    for (int it = 0; it < 8; ++it) {
        int f = 4 * (t + 256 * it);                // flat float index in 128x64
        int k = f >> 6, c = f & 63;
        float4 v = *(const float4*)&W1[f];
        ws[(c + 0) * WS_LD + k] = v.x;
        ws[(c + 1) * WS_LD + k] = v.y;
        ws[(c + 2) * WS_LD + k] = v.z;
        ws[(c + 3) * WS_LD + k] = v.w;
    }
    __syncthreads();

    const int tx = t & 15, ty = t >> 4;
    float acc[4][4];
    #pragma unroll
    for (int i = 0; i < 4; ++i)
        #pragma unroll
        for (int j = 0; j < 4; ++j) acc[i][j] = 0.f;

    for (int k0 = 0; k0 < NFEAT; k0 += 4) {
        float4 a[4], b[4];
        #pragma unroll
        for (int i = 0; i < 4; ++i)
            a[i] = *(const float4*)&xs[(4 * ty + i) * XS_LD + k0];
        #pragma unroll
        for (int j = 0; j < 4; ++j)
            b[j] = *(const float4*)&ws[(tx + 16 * j) * WS_LD + k0];
        #pragma unroll
        for (int i = 0; i < 4; ++i)
            #pragma unroll
            for (int j = 0; j < 4; ++j)
                acc[i][j] += a[i].x * b[j].x + a[i].y * b[j].y +
                             a[i].z * b[j].z + a[i].w * b[j].w;
    }

    #pragma unroll
    for (int i = 0; i < 4; ++i) {
        int n = bm + 4 * ty + i;
        if (n < N_NODES) {
            float dn = dis[n];
            #pragma unroll
            for (int j = 0; j < 4; ++j)
                sxw[(size_t)n * NHID + tx + 16 * j] =
                    __float2bfloat16(acc[i][j] * dn);
        }
    }
}

// act1[n] = relu( dn * ( sxw[n] + sum_{r in N(n)} sxw[r] ) + b1 )
// where sxw[r] = bf16(dis[r]*xw[r]).  One wave per node, lane = feature;
// per-edge read = 64 lanes x 2B = 128B coalesced. 4-way unrolled.
__global__ __launch_bounds__(256) void k_gather1(const __hip_bfloat16* __restrict__ sxw,
                                                 const int* __restrict__ ptr,
                                                 const int* __restrict__ cnt,
                                                 const int* __restrict__ eidx,
                                                 const float* __restrict__ dis,
                                                 const float* __restrict__ b1,
                                                 float* __restrict__ act1) {
    const int lane = threadIdx.x & 63;
    const int wave = threadIdx.x >> 6;
    const int n = blockIdx.x * 4 + wave;
    if (n >= N_NODES) return;
    const float dn = dis[n];
    const int p0 = ptr[n];
    const int pend = p0 + cnt[n];
    float a0 = __bfloat162float(sxw[(size_t)n * NHID + lane]);   // self term
    float a1 = 0.f, a2 = 0.f, a3 = 0.f;
    int e = p0;
    for (; e + 4 <= pend; e += 4) {
        int r0 = eidx[e + 0], r1 = eidx[e + 1], r2 = eidx[e + 2], r3 = eidx[e + 3];
        a0 += __bfloat162float(sxw[(size_t)r0 * NHID + lane]);
        a1 += __bfloat162float(sxw[(size_t)r1 * NHID + lane]);
        a2 += __bfloat162float(sxw[(size_t)r2 * NHID + lane]);
        a3 += __bfloat162float(sxw[(size_t)r3 * NHID + lane]);
    }
    for (; e < pend; ++e) {
        int r = eidx[e];
        a1 += __bfloat162float(sxw[(size_t)r * NHID + lane]);
    }
    float acc = dn * ((a0 + a1) + (a2 + a3));
    act1[(size_t)n * NHID + lane] = fmaxf(acc + b1[lane], 0.f);
}

// xw2 = act1 @ W2.  One thread per (node, class); W2 (4 KB) L1-resident.
__global__ __launch_bounds__(256) void k_gemm2(const float* __restrict__ act1,
                                               const float* __restrict__ W2,
                                               float* __restrict__ xw2) {
    int tid = blockIdx.x * blockDim.x + threadIdx.x;
    if (tid >= N_NODES * NCLASS) return;
    int n = tid >> 4, cc = tid & 15;
    const float* ar = act1 + (size_t)n * NHID;
    float acc = 0.f;
    #pragma unroll
    for (int k = 0; k < NHID; k += 4) {
        float4 a = *(const float4*)&ar[k];
        acc += a.x * W2[(k + 0) * NCLASS + cc] + a.y * W2[(k + 1) * NCLASS + cc] +
               a.z * W2[(k + 2) * NCLASS + cc] + a.w * W2[(k + 3) * NCLASS + cc];
    }
    xw2[tid] = acc;
}

// Layer-2 aggregate + b2 + log_softmax fused.
__global__ __launch_bounds__(256) void k_gather2(const float* __restrict__ xw2,
                                                 const int* __restrict__ ptr,
                                                 const int* __restrict__ cnt,
                                                 const int* __restrict__ eidx,
                                                 const float* __restrict__ dis,
                                                 const float* __restrict__ b2,
                                                 float* __restrict__ out) {
    const int lane = threadIdx.x & 63;
    const int wave = threadIdx.x >> 6;
    const int n = blockIdx.x * 4 + wave;
    if (n >= N_NODES) return;
    const int f = lane & 15;
    const int g = lane >> 4;
    const float dn = dis[n];
    float acc = (g == 0) ? dn * dn * xw2[(size_t)n * NCLASS + f] : 0.f;
    const int p0 = ptr[n];
    const int c = cnt[n];
    for (int e = p0 + g; e < p0 + c; e += 4) {
        int r = eidx[e];
        acc += dn * dis[r] * xw2[(size_t)r * NCLASS + f];
    }
    acc += __shfl_xor(acc, 16);
    acc += __shfl_xor(acc, 32);
    float v = acc + b2[f];
    float m = v;
    m = fmaxf(m, __shfl_xor(m, 1));
    m = fmaxf(m, __shfl_xor(m, 2));
    m = fmaxf(m, __shfl_xor(m, 4));
    m = fmaxf(m, __shfl_xor(m, 8));
    float ex = expf(v - m);
    float s = ex;
    s += __shfl_xor(s, 1);
    s += __shfl_xor(s, 2);
    s += __shfl_xor(s, 4);
    s += __shfl_xor(s, 8);
    float res = (v - m) - logf(s);
    if (lane < 16) out[(size_t)n * NCLASS + lane] = res;
}

// ---------------------------------------------------------------------------

static inline size_t align256(size_t x) { return (x + 255) & ~(size_t)255; }

extern "C" void kernel_launch(void* const* d_in, const int* in_sizes, int n_in,
                              void* d_out, int out_size, void* d_ws, size_t ws_size,
                              hipStream_t stream) {
    const float* x  = (const float*)d_in[0];
    const int*   ei = (const int*)d_in[1];        // [2, E] flat: row then col
    const float* W1 = (const float*)d_in[2];
    const float* b1 = (const float*)d_in[3];
    const float* W2 = (const float*)d_in[4];
    const float* b2 = (const float*)d_in[5];
    float* out = (float*)d_out;

    const int* rowv = ei;                         // edge_index[0] = sources
    const int* colv = ei + N_EDGES;               // edge_index[1] = targets

    char* ws = (char*)d_ws;
    size_t off = 0;
    int*   cnt    = (int*)(ws + off);  off = align256(off + sizeof(int)   * N_NODES);
    int*   ptr    = (int*)(ws + off);  off = align256(off + sizeof(int)   * N_NODES);
    int*   cursor = (int*)(ws + off);  off = align256(off + sizeof(int)   * N_NODES);
    int*   eidx   = (int*)(ws + off);  off = align256(off + sizeof(int)   * N_EDGES);
    float* dis    = (float*)(ws + off); off = align256(off + sizeof(float) * N_NODES);
    int*   bsum   = (int*)(ws + off);  off = align256(off + sizeof(int)   * 512);
    int*   bbase  = (int*)(ws + off);  off = align256(off + sizeof(int)   * 512);
    __hip_bfloat16* sxw = (__hip_bfloat16*)(ws + off);
    off = align256(off + sizeof(__hip_bfloat16) * N_NODES * NHID);
    float* act1   = (float*)(ws + off); off = align256(off + sizeof(float) * N_NODES * NHID);
    float* xw2    = (float*)(ws + off); off = align256(off + sizeof(float) * N_NODES * NCLASS);
    (void)ws_size; (void)n_in; (void)in_sizes; (void)out_size;

    // 1. degree count
    k_zero_cnt<<<512, 256, 0, stream>>>(cnt);
    k_count<<<2048, 256, 0, stream>>>(colv, cnt);
    // 2. multi-block prefix scan -> ptr/cursor, dis
    k_scan_partial<<<SCAN_NB, 256, 0, stream>>>(cnt, bsum);
    k_scan_bases<<<1, 512, 0, stream>>>(bsum, bbase);
    k_scan_apply<<<SCAN_NB, 256, 0, stream>>>(cnt, bbase, ptr, cursor, dis);
    // 3. XCD-partitioned CSR fill
    k_fill<<<2048, 256, 0, stream>>>(rowv, colv, cursor, eidx);
    // 4. layer-1 transform (LDS-tiled GEMM, bf16 pre-scaled output)
    k_gemm1<<<(N_NODES + 63) / 64, 256, 0, stream>>>(x, W1, dis, sxw);
    // 5. layer-1 aggregate + bias + relu (bf16 gather)
    k_gather1<<<(N_NODES + 3) / 4, 256, 0, stream>>>(sxw, ptr, cnt, eidx, dis, b1, act1);
    // 6. layer-2 transform
    k_gemm2<<<(N_NODES * NCLASS + 255) / 256, 256, 0, stream>>>(act1, W2, xw2);
    // 7. layer-2 aggregate + bias + log_softmax
    k_gather2<<<(N_NODES + 3) / 4, 256, 0, stream>>>(xw2, ptr, cnt, eidx, dis, b2, out);
}